// Round 1
// baseline (1241.521 us; speedup 1.0000x reference)
//
#include <hip/hip_runtime.h>

// ---------------- problem constants ----------------
#define LENQ 13294
#define BQ   2
#define MROWS (BQ * LENQ)   // 26588
#define DMODEL 256
#define EPS_LN 1e-5f

// spatial levels
__device__ __constant__ int c_dummy; // keep nothing needed; use constexpr locals

static inline int cdiv(int a, int b) { return (a + b - 1) / b; }

// ---------------- generic tiled fp32 GEMM: C = act(A @ W + bias) ----------------
// A: M x K row-major (optionally A = A1 + A2 elementwise), W: K x N row-major.
// Tile 64x64, BK=16, 256 threads, 4x4 outputs per thread.
template <bool FUSE_ADD, bool RELU>
__global__ __launch_bounds__(256) void gemm_bias(
    const float* __restrict__ A, const float* __restrict__ A2,
    const float* __restrict__ W, const float* __restrict__ bias,
    float* __restrict__ C, int M, int N, int K)
{
    __shared__ float As[16][68];   // k-major, padded
    __shared__ float Bs[16][64];

    const int m0 = blockIdx.x * 64;
    const int n0 = blockIdx.y * 64;
    const int t  = threadIdx.x;
    const int tx = t & 15;         // N direction
    const int ty = t >> 4;         // M direction

    float acc[4][4] = {};

    for (int k0 = 0; k0 < K; k0 += 16) {
        // load A tile: thread t -> row t>>2 (0..63), k (t&3)*4 (float4)
        {
            const int r  = t >> 2;
            const int kk = (t & 3) * 4;
            const int row = m0 + r;
            float4 v = make_float4(0.f, 0.f, 0.f, 0.f);
            if (row < M) {
                v = *reinterpret_cast<const float4*>(A + (size_t)row * K + k0 + kk);
                if (FUSE_ADD) {
                    float4 w2 = *reinterpret_cast<const float4*>(A2 + (size_t)row * K + k0 + kk);
                    v.x += w2.x; v.y += w2.y; v.z += w2.z; v.w += w2.w;
                }
            }
            As[kk + 0][r] = v.x;
            As[kk + 1][r] = v.y;
            As[kk + 2][r] = v.z;
            As[kk + 3][r] = v.w;
        }
        // load B tile: thread t -> k t>>4 (0..15), n (t&15)*4 (float4)
        {
            const int kk = t >> 4;
            const int nn = (t & 15) * 4;
            float4 v = *reinterpret_cast<const float4*>(W + (size_t)(k0 + kk) * N + n0 + nn);
            *reinterpret_cast<float4*>(&Bs[kk][nn]) = v;
        }
        __syncthreads();

        #pragma unroll
        for (int kk = 0; kk < 16; ++kk) {
            float4 a = *reinterpret_cast<const float4*>(&As[kk][ty * 4]);
            float4 b = *reinterpret_cast<const float4*>(&Bs[kk][tx * 4]);
            acc[0][0] += a.x * b.x; acc[0][1] += a.x * b.y; acc[0][2] += a.x * b.z; acc[0][3] += a.x * b.w;
            acc[1][0] += a.y * b.x; acc[1][1] += a.y * b.y; acc[1][2] += a.y * b.z; acc[1][3] += a.y * b.w;
            acc[2][0] += a.z * b.x; acc[2][1] += a.z * b.y; acc[2][2] += a.z * b.z; acc[2][3] += a.z * b.w;
            acc[3][0] += a.w * b.x; acc[3][1] += a.w * b.y; acc[3][2] += a.w * b.z; acc[3][3] += a.w * b.w;
        }
        __syncthreads();
    }

    // epilogue
    const float4 bv = *reinterpret_cast<const float4*>(bias + n0 + tx * 4);
    #pragma unroll
    for (int i = 0; i < 4; ++i) {
        const int row = m0 + ty * 4 + i;
        if (row < M) {
            float4 o;
            o.x = acc[i][0] + bv.x;
            o.y = acc[i][1] + bv.y;
            o.z = acc[i][2] + bv.z;
            o.w = acc[i][3] + bv.w;
            if (RELU) {
                o.x = fmaxf(o.x, 0.f); o.y = fmaxf(o.y, 0.f);
                o.z = fmaxf(o.z, 0.f); o.w = fmaxf(o.w, 0.f);
            }
            *reinterpret_cast<float4*>(C + (size_t)row * N + n0 + tx * 4) = o;
        }
    }
}

// ---------------- fused softmax + multi-scale deformable sampling ----------------
// value:  M x 256  (b, q, h, c) ; off: M x 256 ; logits: M x 128 ; ref: M x 8
// out: M x 256 (b, q, h, c)
__global__ __launch_bounds__(256) void ms_sample(
    const float* __restrict__ value, const float* __restrict__ off,
    const float* __restrict__ logits, const float* __restrict__ ref,
    float* __restrict__ out)
{
    constexpr int LVL_H[4] = {100, 50, 25, 13};
    constexpr int LVL_W[4] = {100, 50, 25, 13};
    constexpr int LVL_S[4] = {0, 10000, 12500, 13125};

    const int row = blockIdx.x;            // b*LEN + q
    const int b   = row / LENQ;
    const int t   = threadIdx.x;
    const int h   = t >> 5;                // head 0..7
    const int c   = t & 31;                // channel 0..31

    const float* lg = logits + (size_t)row * 128 + h * 32;
    float mx = lg[0];
    #pragma unroll
    for (int i = 1; i < 32; ++i) mx = fmaxf(mx, lg[i]);
    float se = 0.f;
    #pragma unroll
    for (int i = 0; i < 32; ++i) se += __expf(lg[i] - mx);
    const float inv = 1.f / se;

    const float* offr = off + (size_t)row * 256;
    const float* refr = ref + (size_t)row * 8;

    float acc = 0.f;
    #pragma unroll
    for (int l = 0; l < 4; ++l) {
        const int H = LVL_H[l], W = LVL_W[l];
        const float* vl = value + ((size_t)(b * LENQ + LVL_S[l])) * 256 + h * 32 + c;
        const float rx = refr[l * 2 + 0];
        const float ry = refr[l * 2 + 1];
        #pragma unroll
        for (int p = 0; p < 4; ++p) {
            const float ox = offr[(((h * 4 + l) * 4 + p) * 2) + 0];
            const float oy = offr[(((h * 4 + l) * 4 + p) * 2) + 1];
            const float locx = rx + ox / (float)W;
            const float locy = ry + oy / (float)H;
            const float x = locx * (float)W - 0.5f;
            const float y = locy * (float)H - 0.5f;
            const float fx = floorf(x), fy = floorf(y);
            const float dx = x - fx, dy = y - fy;
            const int x0 = (int)fx, y0 = (int)fy;
            const float aw = __expf(lg[l * 4 + p] - mx) * inv;

            float sample = 0.f;
            #pragma unroll
            for (int cy = 0; cy < 2; ++cy) {
                #pragma unroll
                for (int cx = 0; cx < 2; ++cx) {
                    const int xi = x0 + cx, yi = y0 + cy;
                    const float wgt = (cx ? dx : 1.f - dx) * (cy ? dy : 1.f - dy);
                    const bool in = (xi >= 0) && (xi < W) && (yi >= 0) && (yi < H);
                    const int xc = min(max(xi, 0), W - 1);
                    const int yc = min(max(yi, 0), H - 1);
                    const float g = vl[(size_t)(yc * W + xc) * 256];
                    sample += g * (in ? wgt : 0.f);
                }
            }
            acc += aw * sample;
        }
    }
    out[(size_t)row * 256 + t] = acc;
}

// ---------------- fused residual + LayerNorm (one wave per row of 256) ----------------
__global__ __launch_bounds__(256) void resid_ln(
    const float* __restrict__ a, const float* __restrict__ r,
    const float* __restrict__ g, const float* __restrict__ be,
    float* __restrict__ out, int M)
{
    const int lane = threadIdx.x & 63;
    const int wid  = threadIdx.x >> 6;
    const int row  = blockIdx.x * 4 + wid;
    if (row >= M) return;

    float4 va = *(reinterpret_cast<const float4*>(a + (size_t)row * 256) + lane);
    float4 vb = *(reinterpret_cast<const float4*>(r + (size_t)row * 256) + lane);
    float4 v;
    v.x = va.x + vb.x; v.y = va.y + vb.y; v.z = va.z + vb.z; v.w = va.w + vb.w;

    float s = v.x + v.y + v.z + v.w;
    #pragma unroll
    for (int m = 1; m < 64; m <<= 1) s += __shfl_xor(s, m);
    const float mean = s * (1.f / 256.f);

    float4 d;
    d.x = v.x - mean; d.y = v.y - mean; d.z = v.z - mean; d.w = v.w - mean;
    float q = d.x * d.x + d.y * d.y + d.z * d.z + d.w * d.w;
    #pragma unroll
    for (int m = 1; m < 64; m <<= 1) q += __shfl_xor(q, m);
    const float rs = rsqrtf(q * (1.f / 256.f) + EPS_LN);

    float4 gv = *(reinterpret_cast<const float4*>(g) + lane);
    float4 bv = *(reinterpret_cast<const float4*>(be) + lane);
    float4 o;
    o.x = d.x * rs * gv.x + bv.x;
    o.y = d.y * rs * gv.y + bv.y;
    o.z = d.z * rs * gv.z + bv.z;
    o.w = d.w * rs * gv.w + bv.w;
    *(reinterpret_cast<float4*>(out + (size_t)row * 256) + lane) = o;
}

// ---------------- launch ----------------
extern "C" void kernel_launch(void* const* d_in, const int* in_sizes, int n_in,
                              void* d_out, int out_size, void* d_ws, size_t ws_size,
                              hipStream_t stream)
{
    const float* src   = (const float*)d_in[0];
    const float* pos   = (const float*)d_in[1];
    const float* refp  = (const float*)d_in[2];
    const float* Wv    = (const float*)d_in[3];
    const float* bv    = (const float*)d_in[4];
    const float* Woff  = (const float*)d_in[5];
    const float* boff  = (const float*)d_in[6];
    const float* Wattn = (const float*)d_in[7];
    const float* battn = (const float*)d_in[8];
    const float* Wout  = (const float*)d_in[9];
    const float* bout  = (const float*)d_in[10];
    const float* W1    = (const float*)d_in[11];
    const float* b1    = (const float*)d_in[12];
    const float* W2    = (const float*)d_in[13];
    const float* b2    = (const float*)d_in[14];
    const float* g1    = (const float*)d_in[15];
    const float* be1   = (const float*)d_in[16];
    const float* g2    = (const float*)d_in[17];
    const float* be2   = (const float*)d_in[18];
    float* out = (float*)d_out;

    float* ws = (float*)d_ws;
    const size_t SZ = (size_t)MROWS * 256;     // 6,806,528 floats
    float* attnout = ws;                        // o0: attnout  (later: h chunk low half)
    float* value   = ws + SZ;                   // o1: value -> src2 (later: h chunk high half)
    float* offb    = ws + 2 * SZ;               // o2: off
    float* logits  = ws + 3 * SZ;               // o3: logits -> ffn

    const dim3 blk(256);
    const int gM  = cdiv(MROWS, 64);            // 416
    const int Mc  = LENQ;                       // 13294 per chunk
    const int gMc = cdiv(Mc, 64);               // 208

    // projections
    gemm_bias<false, false><<<dim3(gM, 4), blk, 0, stream>>>(src, nullptr, Wv, bv, value, MROWS, 256, 256);
    gemm_bias<true,  false><<<dim3(gM, 4), blk, 0, stream>>>(src, pos, Woff, boff, offb, MROWS, 256, 256);
    gemm_bias<true,  false><<<dim3(gM, 2), blk, 0, stream>>>(src, pos, Wattn, battn, logits, MROWS, 128, 256);

    // deformable sampling (softmax fused)
    ms_sample<<<dim3(MROWS), blk, 0, stream>>>(value, offb, logits, refp, attnout);

    // output projection -> src2 (reuse value buffer)
    gemm_bias<false, false><<<dim3(gM, 4), blk, 0, stream>>>(attnout, nullptr, Wout, bout, value, MROWS, 256, 256);

    // LN1: x1 = LN(src + src2) -> d_out
    resid_ln<<<dim3(cdiv(MROWS, 4)), blk, 0, stream>>>(src, value, g1, be1, out, MROWS);

    // FFN in two row-chunks; h reuses o0+o1 (exactly 13294*1024 floats)
    float* hbuf = ws;            // spans o0..o2
    float* ffn  = logits;        // o3 region reused for ffn output (M x 256)
    for (int ch = 0; ch < 2; ++ch) {
        const float* x1c = out + (size_t)ch * Mc * 256;
        float* ffnc = ffn + (size_t)ch * Mc * 256;
        gemm_bias<false, true ><<<dim3(gMc, 16), blk, 0, stream>>>(x1c, nullptr, W1, b1, hbuf, Mc, 1024, 256);
        gemm_bias<false, false><<<dim3(gMc, 4),  blk, 0, stream>>>(hbuf, nullptr, W2, b2, ffnc, Mc, 256, 1024);
    }

    // LN2: out = LN(x1 + ffn) -> d_out (in-place on d_out rows)
    resid_ln<<<dim3(cdiv(MROWS, 4)), blk, 0, stream>>>(out, ffn, g2, be2, out, MROWS);
}

// Round 2
// 280.097 us; speedup vs baseline: 4.4325x; 4.4325x over previous
//
#include <hip/hip_runtime.h>
#include <hip/hip_bf16.h>

// ---------------- problem constants ----------------
#define LENQ 13294
#define BQ   2
#define MROWS (BQ * LENQ)        // 26588
#define PADM  26624              // 208 * 128
#define MT    208                // PADM / 128
#define MC    13294              // FFN chunk rows
#define MTC   104                // 13312 / 128 tiles per chunk
#define EPS_LN 1e-5f

static inline int cdiv(int a, int b) { return (a + b - 1) / b; }

typedef __attribute__((ext_vector_type(8))) short short8;
typedef __attribute__((ext_vector_type(4))) float vf4;

__device__ inline ushort f2bf(float f) {
    __hip_bfloat16 h = __float2bfloat16(f);
    return reinterpret_cast<ushort&>(h);
}

// ---------------- weight convert + transpose: W (K x N fp32) -> Wt (N x K bf16) ----------------
__global__ __launch_bounds__(256) void wconv(const float* __restrict__ W,
                                             ushort* __restrict__ Wt, int K, int N) {
    int i = blockIdx.x * 256 + threadIdx.x;
    if (i >= N * K) return;
    int n = i / K, k = i - n * K;
    Wt[i] = f2bf(W[(size_t)k * N + n]);
}

// ---------------- src/pos -> bf16 src, bf16 (src+pos) ----------------
__global__ __launch_bounds__(256) void conv_src_q(const float* __restrict__ src,
                                                  const float* __restrict__ pos,
                                                  ushort* __restrict__ srcb,
                                                  ushort* __restrict__ qb, int n4) {
    int i = blockIdx.x * 256 + threadIdx.x;
    if (i >= n4) return;
    float4 s = reinterpret_cast<const float4*>(src)[i];
    float4 p = reinterpret_cast<const float4*>(pos)[i];
    ushort4 sb, qv;
    sb.x = f2bf(s.x); sb.y = f2bf(s.y); sb.z = f2bf(s.z); sb.w = f2bf(s.w);
    qv.x = f2bf(s.x + p.x); qv.y = f2bf(s.y + p.y); qv.z = f2bf(s.z + p.z); qv.w = f2bf(s.w + p.w);
    reinterpret_cast<ushort4*>(srcb)[i] = sb;
    reinterpret_cast<ushort4*>(qb)[i]   = qv;
}

// ---------------- bf16 MFMA GEMM: C = act(A @ Bt^T + bias) ----------------
// A: rows x K bf16 row-major (rows = gridDim.x*128, padded). Bt: N x K bf16 row-major.
// 128x128 tile, BK=32, 4 waves each computing 64x64 via 4x4 16x16x32 fragments.
template<bool RELU, bool OUTBF16>
__global__ __launch_bounds__(256) void gemm_mfma(
    const ushort* __restrict__ A, const ushort* __restrict__ Bt,
    const float* __restrict__ bias, float* __restrict__ Cf,
    ushort* __restrict__ Cb, int N, int K)
{
    __shared__ short As[128 * 40];   // row stride 40 shorts (80 B) to spread banks
    __shared__ short Bs[128 * 40];

    const int t    = threadIdx.x;
    const int m0   = blockIdx.x * 128;
    const int n0   = blockIdx.y * 128;
    const int lane = t & 63, wid = t >> 6;
    const int wr   = wid >> 1, wc = wid & 1;
    const int ln   = lane & 15, lr = lane >> 4;

    vf4 acc[4][4];
    #pragma unroll
    for (int m = 0; m < 4; ++m)
        #pragma unroll
        for (int n = 0; n < 4; ++n)
            acc[m][n] = (vf4){0.f, 0.f, 0.f, 0.f};

    // staging map: thread -> row t>>1 (0..127), 32B chunk (t&1)
    const int sr = t >> 1, sc = (t & 1) * 16;
    const ushort* gA = A  + (size_t)(m0 + sr) * K + sc;
    const ushort* gB = Bt + (size_t)(n0 + sr) * K + sc;
    short* wA = &As[sr * 40 + sc];
    short* wB = &Bs[sr * 40 + sc];

    for (int k0 = 0; k0 < K; k0 += 32) {
        int4 a0 = *reinterpret_cast<const int4*>(gA);
        int4 a1 = *reinterpret_cast<const int4*>(gA + 8);
        int4 b0 = *reinterpret_cast<const int4*>(gB);
        int4 b1 = *reinterpret_cast<const int4*>(gB + 8);
        gA += 32; gB += 32;
        __syncthreads();                 // previous iter's frag reads complete
        *reinterpret_cast<int4*>(wA)     = a0;
        *reinterpret_cast<int4*>(wA + 8) = a1;
        *reinterpret_cast<int4*>(wB)     = b0;
        *reinterpret_cast<int4*>(wB + 8) = b1;
        __syncthreads();

        short8 af[4], bfr[4];
        #pragma unroll
        for (int m = 0; m < 4; ++m)
            af[m] = *reinterpret_cast<const short8*>(&As[(wr * 64 + m * 16 + ln) * 40 + lr * 8]);
        #pragma unroll
        for (int n = 0; n < 4; ++n)
            bfr[n] = *reinterpret_cast<const short8*>(&Bs[(wc * 64 + n * 16 + ln) * 40 + lr * 8]);
        #pragma unroll
        for (int m = 0; m < 4; ++m)
            #pragma unroll
            for (int n = 0; n < 4; ++n)
                acc[m][n] = __builtin_amdgcn_mfma_f32_16x16x32_bf16(af[m], bfr[n], acc[m][n], 0, 0, 0);
    }

    // epilogue: C[row, col], col = lane&15, row = (lane>>4)*4 + reg
    #pragma unroll
    for (int n = 0; n < 4; ++n) {
        const int col = n0 + wc * 64 + n * 16 + ln;
        const float bc = bias[col];
        #pragma unroll
        for (int m = 0; m < 4; ++m) {
            const int rbase = m0 + wr * 64 + m * 16 + lr * 4;
            #pragma unroll
            for (int q = 0; q < 4; ++q) {
                float v = acc[m][n][q] + bc;
                if (RELU) v = fmaxf(v, 0.f);
                const size_t o = (size_t)(rbase + q) * N + col;
                if (OUTBF16) Cb[o] = f2bf(v);
                else         Cf[o] = v;
            }
        }
    }
}

// ---------------- fused softmax + multi-scale deformable sampling ----------------
// 1 block = 4 rows. Phase 1: per (r,h,lp) compute aw + 4 gather idx + 4 merged weights -> LDS.
// Phase 2: (r,h,c4) threads gather float4 and accumulate; write bf16 attn output.
__global__ __launch_bounds__(256) void ms_sample(
    const float* __restrict__ value, const float* __restrict__ off,
    const float* __restrict__ logits, const float* __restrict__ ref,
    ushort* __restrict__ outb)
{
    __shared__ int   s_idx[512 * 4];
    __shared__ float s_w[512 * 4];

    const int t    = threadIdx.x;
    const int row0 = blockIdx.x * 4;

    #pragma unroll
    for (int j = 0; j < 2; ++j) {
        const int item = t + j * 256;
        const int r = item >> 7, h = (item >> 4) & 7, lp = item & 15;
        const int l = lp >> 2;
        const int row = row0 + r;
        const int b = (row >= LENQ) ? 1 : 0;

        const float lg = logits[(size_t)row * 128 + h * 16 + lp];
        float mx = lg;
        #pragma unroll
        for (int s2 = 1; s2 < 16; s2 <<= 1) mx = fmaxf(mx, __shfl_xor(mx, s2));
        const float e = __expf(lg - mx);
        float se = e;
        #pragma unroll
        for (int s2 = 1; s2 < 16; s2 <<= 1) se += __shfl_xor(se, s2);
        const float aw = e / se;

        const int LW[4] = {100, 50, 25, 13};
        const int LS[4] = {0, 10000, 12500, 13125};
        const int W = LW[l], H = W;
        const float ox = off[(size_t)row * 256 + (h * 16 + lp) * 2 + 0];
        const float oy = off[(size_t)row * 256 + (h * 16 + lp) * 2 + 1];
        const float rx = ref[(size_t)row * 8 + l * 2 + 0];
        const float ry = ref[(size_t)row * 8 + l * 2 + 1];
        const float x = (rx + ox / (float)W) * (float)W - 0.5f;
        const float y = (ry + oy / (float)H) * (float)H - 0.5f;
        const float fx = floorf(x), fy = floorf(y);
        const float dx = x - fx, dy = y - fy;
        const int x0 = (int)fx, y0 = (int)fy;
        const int base = b * LENQ + LS[l];
        #pragma unroll
        for (int cy = 0; cy < 2; ++cy)
            #pragma unroll
            for (int cx = 0; cx < 2; ++cx) {
                const int c  = cy * 2 + cx;
                const int xi = x0 + cx, yi = y0 + cy;
                const bool in = (xi >= 0) && (xi < W) && (yi >= 0) && (yi < H);
                const int xc = min(max(xi, 0), W - 1);
                const int yc = min(max(yi, 0), H - 1);
                s_idx[item * 4 + c] = base + yc * W + xc;
                s_w[item * 4 + c]   = in ? ((cx ? dx : 1.f - dx) * (cy ? dy : 1.f - dy) * aw) : 0.f;
            }
    }
    __syncthreads();

    // phase 2
    const int r = t >> 6, h = (t >> 3) & 7, c4 = t & 7;
    const int row = row0 + r;
    const float* vb = value + h * 32 + c4 * 4;
    float4 acc = make_float4(0.f, 0.f, 0.f, 0.f);
    const int ib = (r * 8 + h) * 16 * 4;
    #pragma unroll
    for (int lp = 0; lp < 16; ++lp) {
        #pragma unroll
        for (int c = 0; c < 4; ++c) {
            const int idx  = s_idx[ib + lp * 4 + c];
            const float w  = s_w[ib + lp * 4 + c];
            const float4 g = *reinterpret_cast<const float4*>(vb + (size_t)idx * 256);
            acc.x += w * g.x; acc.y += w * g.y; acc.z += w * g.z; acc.w += w * g.w;
        }
    }
    ushort4 o;
    o.x = f2bf(acc.x); o.y = f2bf(acc.y); o.z = f2bf(acc.z); o.w = f2bf(acc.w);
    *reinterpret_cast<ushort4*>(outb + (size_t)row * 256 + h * 32 + c4 * 4) = o;
}

// ---------------- fused residual + LayerNorm (one wave per 256-row), optional bf16 copy ----------------
template<bool WB>
__global__ __launch_bounds__(256) void resid_ln(
    const float* __restrict__ a, const float* __restrict__ r,
    const float* __restrict__ g, const float* __restrict__ be,
    float* __restrict__ out, ushort* __restrict__ ob, int M)
{
    const int lane = threadIdx.x & 63;
    const int wid  = threadIdx.x >> 6;
    const int row  = blockIdx.x * 4 + wid;
    if (row >= M) return;

    float4 va = *(reinterpret_cast<const float4*>(a + (size_t)row * 256) + lane);
    float4 vb = *(reinterpret_cast<const float4*>(r + (size_t)row * 256) + lane);
    float4 v;
    v.x = va.x + vb.x; v.y = va.y + vb.y; v.z = va.z + vb.z; v.w = va.w + vb.w;

    float s = v.x + v.y + v.z + v.w;
    #pragma unroll
    for (int m = 1; m < 64; m <<= 1) s += __shfl_xor(s, m);
    const float mean = s * (1.f / 256.f);

    float4 d;
    d.x = v.x - mean; d.y = v.y - mean; d.z = v.z - mean; d.w = v.w - mean;
    float q = d.x * d.x + d.y * d.y + d.z * d.z + d.w * d.w;
    #pragma unroll
    for (int m = 1; m < 64; m <<= 1) q += __shfl_xor(q, m);
    const float rs = rsqrtf(q * (1.f / 256.f) + EPS_LN);

    float4 gv = *(reinterpret_cast<const float4*>(g) + lane);
    float4 bv = *(reinterpret_cast<const float4*>(be) + lane);
    float4 o;
    o.x = d.x * rs * gv.x + bv.x;
    o.y = d.y * rs * gv.y + bv.y;
    o.z = d.z * rs * gv.z + bv.z;
    o.w = d.w * rs * gv.w + bv.w;
    *(reinterpret_cast<float4*>(out + (size_t)row * 256) + lane) = o;
    if (WB) {
        ushort4 h;
        h.x = f2bf(o.x); h.y = f2bf(o.y); h.z = f2bf(o.z); h.w = f2bf(o.w);
        *(reinterpret_cast<ushort4*>(ob + (size_t)row * 256) + lane) = h;
    }
}

// ---------------- launch ----------------
extern "C" void kernel_launch(void* const* d_in, const int* in_sizes, int n_in,
                              void* d_out, int out_size, void* d_ws, size_t ws_size,
                              hipStream_t stream)
{
    const float* src   = (const float*)d_in[0];
    const float* pos   = (const float*)d_in[1];
    const float* refp  = (const float*)d_in[2];
    const float* Wv    = (const float*)d_in[3];
    const float* bv    = (const float*)d_in[4];
    const float* Woff  = (const float*)d_in[5];
    const float* boff  = (const float*)d_in[6];
    const float* Wattn = (const float*)d_in[7];
    const float* battn = (const float*)d_in[8];
    const float* Wout  = (const float*)d_in[9];
    const float* bout  = (const float*)d_in[10];
    const float* W1    = (const float*)d_in[11];
    const float* b1    = (const float*)d_in[12];
    const float* W2    = (const float*)d_in[13];
    const float* b2    = (const float*)d_in[14];
    const float* g1    = (const float*)d_in[15];
    const float* be1   = (const float*)d_in[16];
    const float* g2    = (const float*)d_in[17];
    const float* be2   = (const float*)d_in[18];
    float* out = (float*)d_out;

    // ---------------- workspace layout (bytes) ----------------
    char* wsb = (char*)d_ws;
    const size_t SB16 = (size_t)PADM * 256 * 2;   // 13,631,488
    ushort* srcb   = (ushort*)(wsb + 0);                 // R0: srcb -> attnout(bf16) -> x1b
    ushort* qb     = (ushort*)(wsb + SB16);              // R1: qb  (later: low half of h)
    float*  logitsb= (float* )(wsb + 2 * SB16);          // R2: logits fp32 (later: high half of h)
    float*  valueb = (float* )(wsb + 3 * SB16);          // R3: value -> src2
    float*  offb   = (float* )(wsb + 3 * SB16 + (size_t)PADM * 256 * 4);  // R4: off -> ffn
    char*   wgt    = wsb + 3 * SB16 + 2 * (size_t)PADM * 256 * 4;
    ushort* wvt    = (ushort*)(wgt);                       // 256x256
    ushort* wofft  = (ushort*)(wgt + 131072);              // 256x256
    ushort* wattnt = (ushort*)(wgt + 262144);              // 128x256
    ushort* woutt  = (ushort*)(wgt + 327680);              // 256x256
    ushort* w1t    = (ushort*)(wgt + 458752);              // 1024x256
    ushort* w2t    = (ushort*)(wgt + 983040);              // 256x1024
    ushort* attnb  = srcb;                                  // reuse R0 after value GEMM
    ushort* x1b    = srcb;                                  // reuse R0 after Wout GEMM
    float*  src2   = valueb;                                // reuse R3 after ms_sample
    float*  ffn    = offb;                                  // reuse R4 after ms_sample
    ushort* hb     = qb;                                    // R1+R2 = 27,262,976 B = 13312x1024 bf16

    const dim3 blk(256);

    // weight convert/transpose
    wconv<<<dim3(256),  blk, 0, stream>>>(Wv,    wvt,    256, 256);
    wconv<<<dim3(256),  blk, 0, stream>>>(Woff,  wofft,  256, 256);
    wconv<<<dim3(128),  blk, 0, stream>>>(Wattn, wattnt, 256, 128);
    wconv<<<dim3(256),  blk, 0, stream>>>(Wout,  woutt,  256, 256);
    wconv<<<dim3(1024), blk, 0, stream>>>(W1,    w1t,    256, 1024);
    wconv<<<dim3(1024), blk, 0, stream>>>(W2,    w2t,    1024, 256);

    // activations -> bf16
    conv_src_q<<<dim3(6647), blk, 0, stream>>>(src, pos, srcb, qb, MROWS * 64);

    // projections (bf16 MFMA)
    gemm_mfma<false, false><<<dim3(MT, 2), blk, 0, stream>>>(srcb, wvt,    bv,    valueb,  nullptr, 256, 256);
    gemm_mfma<false, false><<<dim3(MT, 2), blk, 0, stream>>>(qb,   wofft,  boff,  offb,    nullptr, 256, 256);
    gemm_mfma<false, false><<<dim3(MT, 1), blk, 0, stream>>>(qb,   wattnt, battn, logitsb, nullptr, 128, 256);

    // deformable sampling (softmax fused), writes bf16 attn output into R0
    ms_sample<<<dim3(6647), blk, 0, stream>>>(valueb, offb, logitsb, refp, attnb);

    // output projection -> src2 (R3)
    gemm_mfma<false, false><<<dim3(MT, 2), blk, 0, stream>>>(attnb, woutt, bout, src2, nullptr, 256, 256);

    // LN1: x1 = LN(src + src2) -> d_out (fp32) + x1b (bf16, R0)
    resid_ln<true><<<dim3(6647), blk, 0, stream>>>(src, src2, g1, be1, out, x1b, MROWS);

    // FFN in two row-chunks; h (bf16) lives in R1+R2
    for (int ch = 0; ch < 2; ++ch) {
        const ushort* x1c = x1b + (size_t)ch * MC * 256;
        float* ffnc = ffn + (size_t)ch * MC * 256;
        gemm_mfma<true,  true ><<<dim3(MTC, 8), blk, 0, stream>>>(x1c, w1t, b1, nullptr, hb, 1024, 256);
        gemm_mfma<false, false><<<dim3(MTC, 2), blk, 0, stream>>>(hb,  w2t, b2, ffnc, nullptr, 256, 1024);
    }

    // LN2: out = LN(x1 + ffn) -> d_out
    resid_ln<false><<<dim3(6647), blk, 0, stream>>>(out, ffn, g2, be2, out, nullptr, MROWS);
}